// Round 8
// baseline (213.021 us; speedup 1.0000x reference)
//
#include <hip/hip_runtime.h>
#include <hip/hip_bf16.h>
#include <math.h>

constexpr int B_ = 16;
constexpr int T_ = 10240;
constexpr int C_ = 256;
constexpr int KW = 10;
constexpr int L_ = 2047;
constexpr int N_ = B_ * L_;      // 32752
constexpr int KSTEPS = 12;
constexpr float EPS_ = 1e-5f;
constexpr int QSTR = 32768;      // per-k stride of transposed q (2048*16)

typedef short bf16x8 __attribute__((ext_vector_type(8)));
typedef float f32x4  __attribute__((ext_vector_type(4)));

// -------------------- fused: conv+relu+BN-stats  ∪  W-transpose --------------------
// conv part uses a sliding register window: 5 broadcast ds_reads per dl (was 10).
__global__ __launch_bounds__(256) void stats_wt_kernel(
    const float* __restrict__ x, const float* __restrict__ cw, const float* __restrict__ cb,
    float* __restrict__ ssum, float* __restrict__ ssq,
    const float* __restrict__ tw, __hip_bfloat16* __restrict__ Wt)
{
    __shared__ float smem[64 * 65];
    const int bid = blockIdx.x;
    if (bid < 256) {
        const int b  = bid & 15;
        const int l0 = (bid >> 4) * 128;
        const int cnt = min(128, L_ - l0);
        const int c = threadIdx.x;
        float* xs = smem;
        const float* xb = x + (size_t)b * T_;
        for (int i = threadIdx.x; i < cnt * 5 + 5; i += 256) xs[i] = xb[l0 * 5 + i];
        float w[KW];
#pragma unroll
        for (int j = 0; j < KW; ++j) w[j] = cw[c * KW + j];
        const float bias = cb[c];
        __syncthreads();
        float s = 0.f, s2 = 0.f;
        float xw[KW];
#pragma unroll
        for (int j = 0; j < KW; ++j) xw[j] = xs[j];
#pragma unroll 2
        for (int dl = 0; dl < cnt; ++dl) {
            float v = bias;
#pragma unroll
            for (int j = 0; j < KW; ++j) v = fmaf(xw[j], w[j], v);
            v = fmaxf(v, 0.f);
            s += v;
            s2 = fmaf(v, v, s2);
            // shift window by stride 5; over-read of ≤5 floats stays inside smem
#pragma unroll
            for (int j = 0; j < 5; ++j) xw[j] = xw[j + 5];
#pragma unroll
            for (int j = 0; j < 5; ++j) xw[j + 5] = xs[dl * 5 + 10 + j];
        }
        atomicAdd(&ssum[c], s);
        atomicAdd(&ssq[c], s2);
    } else {
        const int idx = bid - 256;            // 0..191
        const int k  = idx >> 4;
        const int c0 = ((idx & 15) >> 2) * 64, j0 = (idx & 3) * 64;
        float (*tile)[65] = (float(*)[65])smem;
        for (int i = threadIdx.x; i < 64 * 64; i += 256) {
            int c = i >> 6, j = i & 63;
            tile[c][j] = tw[((size_t)k * C_ + (c0 + c)) * C_ + j0 + j];
        }
        __syncthreads();
        for (int i = threadIdx.x; i < 64 * 64; i += 256) {
            int j = i >> 6, c = i & 63;
            Wt[((size_t)k * C_ + (j0 + j)) * C_ + c0 + c] = __float2bfloat16(tile[c][j]);
        }
    }
}

// -------------------- conv+relu+normalize (BN finalize fused) → out0 + Zb -----------
__global__ __launch_bounds__(256) void conv_norm_kernel(
    const float* __restrict__ x, const float* __restrict__ cw, const float* __restrict__ cb,
    const float* __restrict__ ssum, const float* __restrict__ ssq,
    const float* __restrict__ gamma, const float* __restrict__ beta,
    __hip_bfloat16* __restrict__ Zb, float* __restrict__ out0)
{
    const int b  = blockIdx.y;
    const int l0 = blockIdx.x * 32;
    const int cnt = min(32, L_ - l0);
    const int c = threadIdx.x;
    __shared__ float xs[32 * 5 + 8];
    __shared__ float zt[32][257];
    const float* xb = x + (size_t)b * T_;
    for (int i = threadIdx.x; i < cnt * 5 + 5; i += 256) xs[i] = xb[l0 * 5 + i];
    float w[KW];
#pragma unroll
    for (int j = 0; j < KW; ++j) w[j] = cw[c * KW + j];
    const float bias = cb[c];
    const float inv_n = 1.0f / (float)N_;
    const float mu  = ssum[c] * inv_n;
    const float var = ssq[c] * inv_n - mu * mu;
    const float sc  = gamma[c] * rsqrtf(var + EPS_);
    const float sh  = beta[c] - mu * sc;
    __syncthreads();
    for (int dl = 0; dl < cnt; ++dl) {
        float v = bias;
#pragma unroll
        for (int j = 0; j < KW; ++j) v = fmaf(xs[dl * 5 + j], w[j], v);
        v = fmaxf(v, 0.f);
        float z = fmaf(v, sc, sh);
        Zb[((size_t)(b * L_ + l0 + dl)) * C_ + c] = __float2bfloat16(z);
        zt[dl][c] = z;
    }
    __syncthreads();
    const int lq  = threadIdx.x & 31;
    const int cr0 = threadIdx.x >> 5;      // 0..7
    if (lq < cnt) {
#pragma unroll
        for (int i = 0; i < 32; ++i) {
            int cr = cr0 * 32 + i;
            out0[((size_t)(b * C_ + cr)) * L_ + l0 + lq] = zt[lq][cr];
        }
    }
}

// -------------------- q kernel: 8 waves x 32 cols (round-3 structure) ---------------
// DIAGNOSTIC SPLIT this round: launched 4x with k0 = 0,3,6,9 and gridDim.y = 3, so
// each dispatch is ~17 µs → the rocprof top-5 threshold drops from 65 to ~17 µs and
// exposes the true durations of the other pipeline kernels (and probes per-launch
// overhead: if wall rises ~30-45 µs, launches cost ~10-15 µs each → fuse next).
__global__ __launch_bounds__(512, 4) void qmfma_kernel(
    const __hip_bfloat16* __restrict__ Zb, const __hip_bfloat16* __restrict__ Wt,
    const float* __restrict__ tb, float* __restrict__ qt, int k0)
{
    const int k   = blockIdx.y + k0;
    const int grp = blockIdx.x;
    const __hip_bfloat16* __restrict__ Wk = Wt + (size_t)k * C_ * C_;

    __shared__ __hip_bfloat16 zs[4][32 * 256];   // 16B chunk j of row r at slot j^(r&7)
    __shared__ float qacc[8][256];

    const int tid  = threadIdx.x;
    const int lane = tid & 63, wave = tid >> 6;   // wave 0..7
    const int n16  = lane & 15, quad = lane >> 4;
    const int sw   = n16 & 7;
    const int row0 = grp * 8 * 32;

    // ---- W resident: col = 32*wave + ct*16 + n16 ; kk = it*32 + quad*8 + j ----
    bf16x8 wfrag[2][8];
    {
        const __hip_bfloat16* wb = Wk + ((size_t)(32 * wave + n16)) * C_ + quad * 8;
#pragma unroll
        for (int ct = 0; ct < 2; ++ct)
#pragma unroll
            for (int it = 0; it < 8; ++it)
                wfrag[ct][it] = *(const bf16x8*)(wb + ct * 16 * C_ + it * 32);
    }
    float4 bias4[2];
#pragma unroll
    for (int ct = 0; ct < 2; ++ct)
        bias4[ct] = *(const float4*)(tb + k * C_ + 32 * wave + ct * 16 + quad * 4);

    // staging: per wave 2 instrs; instr i covers chunks i*512 + wave*64 + lane
#define STAGE(buf, t) do {                                                                  \
    _Pragma("unroll")                                                                       \
    for (int i_ = 0; i_ < 2; ++i_) {                                                        \
        int ch = i_ * 512 + wave * 64 + lane;                                               \
        int rr = ch >> 5;                                                                   \
        int rg = row0 + (t) * 32 + rr; if (rg > N_ - 1) rg = N_ - 1;                        \
        int jj = (lane & 31) ^ (rr & 7);                                                    \
        __builtin_amdgcn_global_load_lds(                                                   \
            (const __attribute__((address_space(1))) void*)(Zb + (size_t)rg * C_ + jj * 8), \
            (__attribute__((address_space(3))) void*)(&zs[buf][i_ * 4096 + wave * 512]),    \
            16, 0, 0);                                                                      \
    }                                                                                       \
} while (0)

    // prologue: stage tiles 0 and 1, drain once (also drains wfrag/bias loads)
    STAGE(0, 0);
    STAGE(1, 1);
    asm volatile("s_waitcnt vmcnt(0)" ::: "memory");

#pragma unroll
    for (int t = 0; t < 8; ++t) {
        if (t < 6) STAGE((t + 2) & 3, t + 2);
        if (t < 6)                { asm volatile("s_waitcnt vmcnt(4)" ::: "memory"); }
        else if (t == 6)          { asm volatile("s_waitcnt vmcnt(2)" ::: "memory"); }
        else                      { asm volatile("s_waitcnt vmcnt(0)" ::: "memory"); }
        __builtin_amdgcn_s_barrier();

        const __hip_bfloat16* zsp = (const __hip_bfloat16*)zs[t & 3];

        f32x4 acc[2][2];
#pragma unroll
        for (int rt = 0; rt < 2; ++rt)
#pragma unroll
            for (int ct = 0; ct < 2; ++ct) acc[rt][ct] = f32x4{0.f, 0.f, 0.f, 0.f};

        __builtin_amdgcn_s_setprio(1);
#pragma unroll
        for (int it = 0; it < 8; ++it) {
            const int js = (it * 4 + quad) ^ sw;
            bf16x8 zf0 = *(const bf16x8*)(zsp + n16 * 256 + js * 8);
            bf16x8 zf1 = *(const bf16x8*)(zsp + (n16 + 16) * 256 + js * 8);
#pragma unroll
            for (int ct = 0; ct < 2; ++ct) {
                acc[0][ct] = __builtin_amdgcn_mfma_f32_16x16x32_bf16(
                    wfrag[ct][it], zf0, acc[0][ct], 0, 0, 0);
                acc[1][ct] = __builtin_amdgcn_mfma_f32_16x16x32_bf16(
                    wfrag[ct][it], zf1, acc[1][ct], 0, 0, 0);
            }
        }
        __builtin_amdgcn_s_setprio(0);

        // ---- epilogue: zrow = rt*16+n16 ; wcols = 32w + ct*16 + quad*4 + r ----
#pragma unroll
        for (int rt = 0; rt < 2; ++rt) {
            const int row = rt * 16 + n16;
            float s = 0.f;
#pragma unroll
            for (int ct = 0; ct < 2; ++ct) {
                const int j  = 4 * wave + 2 * ct + (quad >> 1);
                const char* zp = (const char*)zsp + row * 512 + ((j ^ sw) << 4) + (quad & 1) * 8;
                uint2 zz = *(const uint2*)zp;
                float z0 = __uint_as_float(zz.x << 16);
                float z1 = __uint_as_float(zz.x & 0xffff0000u);
                float z2 = __uint_as_float(zz.y << 16);
                float z3 = __uint_as_float(zz.y & 0xffff0000u);
                s = fmaf(acc[rt][ct][0] + bias4[ct].x, z0, s);
                s = fmaf(acc[rt][ct][1] + bias4[ct].y, z1, s);
                s = fmaf(acc[rt][ct][2] + bias4[ct].z, z2, s);
                s = fmaf(acc[rt][ct][3] + bias4[ct].w, z3, s);
            }
            s += __shfl_xor(s, 16);
            s += __shfl_xor(s, 32);
            if (lane < 16) qacc[wave][t * 32 + row] = s;   // wave-private slice
        }
        // no end-of-tile barrier: buffer t&3 is next overwritten at iter t+2,
        // separated by the top barrier of iter t+1.
    }
#undef STAGE

    __syncthreads();
    // ---- block-end: reduce 8 wave partials per row, write transposed qt ----
    if (tid < 256) {
        int rg = row0 + tid;
        if (rg < N_) {
            float qv = 0.f;
#pragma unroll
            for (int w2 = 0; w2 < 8; ++w2) qv += qacc[w2][tid];
            int b = rg / L_;
            int l = rg - b * L_;
            qt[(size_t)k * QSTR + (l << 4) + b] = qv;
        }
    }
}

// -------------------- loss: gathers + fast exp/log LSE ------------------------------
__global__ __launch_bounds__(256) void loss_kernel(
    const float* __restrict__ qt, const int* __restrict__ perm, float* __restrict__ lacc)
{
    const int k = blockIdx.y + 1;                 // 1..12
    const float* qk = qt + (size_t)(k - 1) * QSTR;
    const int nval = B_ * (L_ - k);
    const int idx = blockIdx.x * 256 + threadIdx.x;

    float contrib = 0.f;
    if (idx < nval) {
        int b = idx & 15;
        int l = k + (idx >> 4);
        float f0 = qk[(l << 4) | b];
        int pl = perm[l];
        const float* qn = qk + ((size_t)pl << 4);
        float f[10];
#pragma unroll
        for (int n = 0; n < 10; ++n) f[n] = qn[(b + 15 - n) & 15];
        float m = f0;
#pragma unroll
        for (int i = 0; i < 10; ++i) m = fmaxf(m, f[i]);
        float se = __expf(f0 - m), fs = f0;
#pragma unroll
        for (int i = 0; i < 10; ++i) { se += __expf(f[i] - m); fs += f[i]; }
        contrib = 11.f * (m + __logf(se)) - fs;
    }

    __shared__ float red[4];
#pragma unroll
    for (int off = 32; off > 0; off >>= 1) contrib += __shfl_down(contrib, off);
    const int lane = threadIdx.x & 63;
    const int wave = threadIdx.x >> 6;
    if (lane == 0) red[wave] = contrib;
    __syncthreads();
    if (threadIdx.x == 0) atomicAdd(&lacc[k - 1], red[0] + red[1] + red[2] + red[3]);
}

__global__ void finalize_loss_kernel(const float* __restrict__ lacc, float* __restrict__ out1)
{
    int k = threadIdx.x;
    if (k < KSTEPS) {
        float div = (float)((L_ - 2 * (k + 1)) * B_);
        out1[k] = lacc[k] / div;
    }
}

// -------------------- launch --------------------
extern "C" void kernel_launch(void* const* d_in, const int* in_sizes, int n_in,
                              void* d_out, int out_size, void* d_ws, size_t ws_size,
                              hipStream_t stream)
{
    const float* x     = (const float*)d_in[0];
    const float* cw    = (const float*)d_in[1];
    const float* cb    = (const float*)d_in[2];
    const float* gamma = (const float*)d_in[3];
    const float* beta  = (const float*)d_in[4];
    const float* tw    = (const float*)d_in[5];
    const float* tb    = (const float*)d_in[6];
    const int*   perm  = (const int*)d_in[7];

    float* out0 = (float*)d_out;
    float* out1 = out0 + (size_t)B_ * C_ * L_;

    char* ws = (char*)d_ws;
    __hip_bfloat16* Zb = (__hip_bfloat16*)ws;   ws += (size_t)N_ * C_ * 2;
    __hip_bfloat16* Wt = (__hip_bfloat16*)ws;   ws += (size_t)KSTEPS * C_ * C_ * 2;
    float* qt    = (float*)ws;                  ws += (size_t)KSTEPS * QSTR * 4;
    float* ssum  = (float*)ws;                  ws += C_ * 4;
    float* ssq   = (float*)ws;                  ws += C_ * 4;
    float* lacc  = (float*)ws;                  ws += 64 * 4;

    hipMemsetAsync(ssum, 0, (C_ + C_ + 64) * sizeof(float), stream);

    stats_wt_kernel<<<448, 256, 0, stream>>>(x, cw, cb, ssum, ssq, tw, Wt);

    dim3 gcv(64, 16);
    conv_norm_kernel<<<gcv, 256, 0, stream>>>(x, cw, cb, ssum, ssq, gamma, beta, Zb, out0);

    // diagnostic 4-way k-split (visibility threshold ~17 µs + launch-overhead probe)
    for (int k0 = 0; k0 < KSTEPS; k0 += 3) {
        dim3 gq(128, 3);
        qmfma_kernel<<<gq, 512, 0, stream>>>(Zb, Wt, tb, qt, k0);
    }

    dim3 gl(128, KSTEPS);
    loss_kernel<<<gl, 256, 0, stream>>>(qt, perm, lacc);
    finalize_loss_kernel<<<1, 64, 0, stream>>>(lacc, out1);
}

// Round 9
// 208.641 us; speedup vs baseline: 1.0210x; 1.0210x over previous
//
#include <hip/hip_runtime.h>
#include <hip/hip_bf16.h>
#include <math.h>

constexpr int B_ = 16;
constexpr int T_ = 10240;
constexpr int C_ = 256;
constexpr int KW = 10;
constexpr int L_ = 2047;
constexpr int N_ = B_ * L_;      // 32752
constexpr int KSTEPS = 12;
constexpr float EPS_ = 1e-5f;
constexpr int QSTR = 32768;      // per-k stride of transposed q (2048*16)

typedef short bf16x8 __attribute__((ext_vector_type(8)));
typedef float f32x4  __attribute__((ext_vector_type(4)));

// -------------------- fused: conv+relu+BN-stats (per-channel blocks)  ∪  W-transpose
// No atomics, no memset: block c owns channel c, sums over all (b,l) via LDS-staged
// x[b] slices (40 KB), writes ssum[c]/ssq[c] directly. Blocks 256..447 transpose W.
__global__ __launch_bounds__(256) void stats_wt_kernel(
    const float* __restrict__ x, const float* __restrict__ cw, const float* __restrict__ cb,
    float* __restrict__ ssum, float* __restrict__ ssq,
    const float* __restrict__ tw, __hip_bfloat16* __restrict__ Wt)
{
    __shared__ float smem[T_];               // x[b] slice (40 KB); transpose reuses 16.6 KB
    __shared__ float redS[4], redQ[4];
    const int bid = blockIdx.x;
    const int tid = threadIdx.x;
    if (bid < 256) {
        const int c = bid;
        float w[KW];
#pragma unroll
        for (int j = 0; j < KW; ++j) w[j] = cw[c * KW + j];
        const float bias = cb[c];
        float s = 0.f, s2 = 0.f;
        for (int b = 0; b < B_; ++b) {
            __syncthreads();
            const float4* xb4 = (const float4*)(x + (size_t)b * T_);
            for (int i = tid; i < T_ / 4; i += 256) ((float4*)smem)[i] = xb4[i];
            __syncthreads();
#pragma unroll
            for (int i = 0; i < 8; ++i) {
                int l = i * 256 + tid;
                if (l < L_) {
                    float v = bias;
#pragma unroll
                    for (int j = 0; j < KW; ++j) v = fmaf(smem[l * 5 + j], w[j], v);
                    v = fmaxf(v, 0.f);
                    s += v;
                    s2 = fmaf(v, v, s2);
                }
            }
        }
        // block reduce (4 waves)
#pragma unroll
        for (int off = 32; off > 0; off >>= 1) {
            s  += __shfl_down(s, off);
            s2 += __shfl_down(s2, off);
        }
        const int lane = tid & 63, wave = tid >> 6;
        if (lane == 0) { redS[wave] = s; redQ[wave] = s2; }
        __syncthreads();
        if (tid == 0) {
            ssum[c] = redS[0] + redS[1] + redS[2] + redS[3];
            ssq[c]  = redQ[0] + redQ[1] + redQ[2] + redQ[3];
        }
    } else {
        const int idx = bid - 256;            // 0..191
        const int k  = idx >> 4;
        const int c0 = ((idx & 15) >> 2) * 64, j0 = (idx & 3) * 64;
        float (*tile)[65] = (float(*)[65])smem;
        for (int i = tid; i < 64 * 64; i += 256) {
            int c = i >> 6, j = i & 63;
            tile[c][j] = tw[((size_t)k * C_ + (c0 + c)) * C_ + j0 + j];
        }
        __syncthreads();
        for (int i = tid; i < 64 * 64; i += 256) {
            int j = i >> 6, c = i & 63;
            Wt[((size_t)k * C_ + (j0 + j)) * C_ + c0 + c] = __float2bfloat16(tile[c][j]);
        }
    }
}

// -------------------- conv+relu+normalize (BN finalize fused) → out0 + Zb -----------
__global__ __launch_bounds__(256) void conv_norm_kernel(
    const float* __restrict__ x, const float* __restrict__ cw, const float* __restrict__ cb,
    const float* __restrict__ ssum, const float* __restrict__ ssq,
    const float* __restrict__ gamma, const float* __restrict__ beta,
    __hip_bfloat16* __restrict__ Zb, float* __restrict__ out0)
{
    const int b  = blockIdx.y;
    const int l0 = blockIdx.x * 32;
    const int cnt = min(32, L_ - l0);
    const int c = threadIdx.x;
    __shared__ float xs[32 * 5 + 8];
    __shared__ float zt[32][257];
    const float* xb = x + (size_t)b * T_;
    for (int i = threadIdx.x; i < cnt * 5 + 5; i += 256) xs[i] = xb[l0 * 5 + i];
    float w[KW];
#pragma unroll
    for (int j = 0; j < KW; ++j) w[j] = cw[c * KW + j];
    const float bias = cb[c];
    const float inv_n = 1.0f / (float)N_;
    const float mu  = ssum[c] * inv_n;
    const float var = ssq[c] * inv_n - mu * mu;
    const float sc  = gamma[c] * rsqrtf(var + EPS_);
    const float sh  = beta[c] - mu * sc;
    __syncthreads();
    for (int dl = 0; dl < cnt; ++dl) {
        float v = bias;
#pragma unroll
        for (int j = 0; j < KW; ++j) v = fmaf(xs[dl * 5 + j], w[j], v);
        v = fmaxf(v, 0.f);
        float z = fmaf(v, sc, sh);
        Zb[((size_t)(b * L_ + l0 + dl)) * C_ + c] = __float2bfloat16(z);
        zt[dl][c] = z;
    }
    __syncthreads();
    const int lq  = threadIdx.x & 31;
    const int cr0 = threadIdx.x >> 5;      // 0..7
    if (lq < cnt) {
#pragma unroll
        for (int i = 0; i < 32; ++i) {
            int cr = cr0 * 32 + i;
            out0[((size_t)(b * C_ + cr)) * L_ + l0 + lq] = zt[lq][cr];
        }
    }
}

// -------------------- q kernel: 8 waves x 32 cols (round-3 best, single launch) -----
__global__ __launch_bounds__(512, 4) void qmfma_kernel(
    const __hip_bfloat16* __restrict__ Zb, const __hip_bfloat16* __restrict__ Wt,
    const float* __restrict__ tb, float* __restrict__ qt)
{
    const int k   = blockIdx.y;
    const int grp = blockIdx.x;
    const __hip_bfloat16* __restrict__ Wk = Wt + (size_t)k * C_ * C_;

    __shared__ __hip_bfloat16 zs[4][32 * 256];   // 16B chunk j of row r at slot j^(r&7)
    __shared__ float qacc[8][256];

    const int tid  = threadIdx.x;
    const int lane = tid & 63, wave = tid >> 6;   // wave 0..7
    const int n16  = lane & 15, quad = lane >> 4;
    const int sw   = n16 & 7;
    const int row0 = grp * 8 * 32;

    // ---- W resident: col = 32*wave + ct*16 + n16 ; kk = it*32 + quad*8 + j ----
    bf16x8 wfrag[2][8];
    {
        const __hip_bfloat16* wb = Wk + ((size_t)(32 * wave + n16)) * C_ + quad * 8;
#pragma unroll
        for (int ct = 0; ct < 2; ++ct)
#pragma unroll
            for (int it = 0; it < 8; ++it)
                wfrag[ct][it] = *(const bf16x8*)(wb + ct * 16 * C_ + it * 32);
    }
    float4 bias4[2];
#pragma unroll
    for (int ct = 0; ct < 2; ++ct)
        bias4[ct] = *(const float4*)(tb + k * C_ + 32 * wave + ct * 16 + quad * 4);

    // staging: per wave 2 instrs; instr i covers chunks i*512 + wave*64 + lane
#define STAGE(buf, t) do {                                                                  \
    _Pragma("unroll")                                                                       \
    for (int i_ = 0; i_ < 2; ++i_) {                                                        \
        int ch = i_ * 512 + wave * 64 + lane;                                               \
        int rr = ch >> 5;                                                                   \
        int rg = row0 + (t) * 32 + rr; if (rg > N_ - 1) rg = N_ - 1;                        \
        int jj = (lane & 31) ^ (rr & 7);                                                    \
        __builtin_amdgcn_global_load_lds(                                                   \
            (const __attribute__((address_space(1))) void*)(Zb + (size_t)rg * C_ + jj * 8), \
            (__attribute__((address_space(3))) void*)(&zs[buf][i_ * 4096 + wave * 512]),    \
            16, 0, 0);                                                                      \
    }                                                                                       \
} while (0)

    // prologue: stage tiles 0 and 1, drain once (also drains wfrag/bias loads)
    STAGE(0, 0);
    STAGE(1, 1);
    asm volatile("s_waitcnt vmcnt(0)" ::: "memory");

#pragma unroll
    for (int t = 0; t < 8; ++t) {
        if (t < 6) STAGE((t + 2) & 3, t + 2);
        if (t < 6)                { asm volatile("s_waitcnt vmcnt(4)" ::: "memory"); }
        else if (t == 6)          { asm volatile("s_waitcnt vmcnt(2)" ::: "memory"); }
        else                      { asm volatile("s_waitcnt vmcnt(0)" ::: "memory"); }
        __builtin_amdgcn_s_barrier();

        const __hip_bfloat16* zsp = (const __hip_bfloat16*)zs[t & 3];

        f32x4 acc[2][2];
#pragma unroll
        for (int rt = 0; rt < 2; ++rt)
#pragma unroll
            for (int ct = 0; ct < 2; ++ct) acc[rt][ct] = f32x4{0.f, 0.f, 0.f, 0.f};

        __builtin_amdgcn_s_setprio(1);
#pragma unroll
        for (int it = 0; it < 8; ++it) {
            const int js = (it * 4 + quad) ^ sw;
            bf16x8 zf0 = *(const bf16x8*)(zsp + n16 * 256 + js * 8);
            bf16x8 zf1 = *(const bf16x8*)(zsp + (n16 + 16) * 256 + js * 8);
#pragma unroll
            for (int ct = 0; ct < 2; ++ct) {
                acc[0][ct] = __builtin_amdgcn_mfma_f32_16x16x32_bf16(
                    wfrag[ct][it], zf0, acc[0][ct], 0, 0, 0);
                acc[1][ct] = __builtin_amdgcn_mfma_f32_16x16x32_bf16(
                    wfrag[ct][it], zf1, acc[1][ct], 0, 0, 0);
            }
        }
        __builtin_amdgcn_s_setprio(0);

        // ---- epilogue: zrow = rt*16+n16 ; wcols = 32w + ct*16 + quad*4 + r ----
#pragma unroll
        for (int rt = 0; rt < 2; ++rt) {
            const int row = rt * 16 + n16;
            float s = 0.f;
#pragma unroll
            for (int ct = 0; ct < 2; ++ct) {
                const int j  = 4 * wave + 2 * ct + (quad >> 1);
                const char* zp = (const char*)zsp + row * 512 + ((j ^ sw) << 4) + (quad & 1) * 8;
                uint2 zz = *(const uint2*)zp;
                float z0 = __uint_as_float(zz.x << 16);
                float z1 = __uint_as_float(zz.x & 0xffff0000u);
                float z2 = __uint_as_float(zz.y << 16);
                float z3 = __uint_as_float(zz.y & 0xffff0000u);
                s = fmaf(acc[rt][ct][0] + bias4[ct].x, z0, s);
                s = fmaf(acc[rt][ct][1] + bias4[ct].y, z1, s);
                s = fmaf(acc[rt][ct][2] + bias4[ct].z, z2, s);
                s = fmaf(acc[rt][ct][3] + bias4[ct].w, z3, s);
            }
            s += __shfl_xor(s, 16);
            s += __shfl_xor(s, 32);
            if (lane < 16) qacc[wave][t * 32 + row] = s;   // wave-private slice
        }
        // no end-of-tile barrier: buffer t&3 is next overwritten at iter t+2,
        // separated by the top barrier of iter t+1.
    }
#undef STAGE

    __syncthreads();
    // ---- block-end: reduce 8 wave partials per row, write transposed qt ----
    if (tid < 256) {
        int rg = row0 + tid;
        if (rg < N_) {
            float qv = 0.f;
#pragma unroll
            for (int w2 = 0; w2 < 8; ++w2) qv += qacc[w2][tid];
            int b = rg / L_;
            int l = rg - b * L_;
            qt[(size_t)k * QSTR + (l << 4) + b] = qv;
        }
    }
}

// -------------------- loss: gathers + fast LSE → per-block partials (no atomics) -----
__global__ __launch_bounds__(256) void loss_kernel(
    const float* __restrict__ qt, const int* __restrict__ perm, float* __restrict__ lpart)
{
    const int k = blockIdx.y + 1;                 // 1..12
    const float* qk = qt + (size_t)(k - 1) * QSTR;
    const int nval = B_ * (L_ - k);
    const int idx = blockIdx.x * 256 + threadIdx.x;

    float contrib = 0.f;
    if (idx < nval) {
        int b = idx & 15;
        int l = k + (idx >> 4);
        float f0 = qk[(l << 4) | b];
        int pl = perm[l];
        const float* qn = qk + ((size_t)pl << 4);
        float f[10];
#pragma unroll
        for (int n = 0; n < 10; ++n) f[n] = qn[(b + 15 - n) & 15];
        float m = f0;
#pragma unroll
        for (int i = 0; i < 10; ++i) m = fmaxf(m, f[i]);
        float se = __expf(f0 - m), fs = f0;
#pragma unroll
        for (int i = 0; i < 10; ++i) { se += __expf(f[i] - m); fs += f[i]; }
        contrib = 11.f * (m + __logf(se)) - fs;
    }

    __shared__ float red[4];
#pragma unroll
    for (int off = 32; off > 0; off >>= 1) contrib += __shfl_down(contrib, off);
    const int lane = threadIdx.x & 63;
    const int wave = threadIdx.x >> 6;
    if (lane == 0) red[wave] = contrib;
    __syncthreads();
    if (threadIdx.x == 0)
        lpart[(size_t)(k - 1) * 128 + blockIdx.x] = red[0] + red[1] + red[2] + red[3];
}

// 12 waves, wave k sums its 128 partials and divides — no lacc, no memset.
__global__ __launch_bounds__(768) void finalize_loss_kernel(
    const float* __restrict__ lpart, float* __restrict__ out1)
{
    const int w = threadIdx.x >> 6;               // k index 0..11
    const int lane = threadIdx.x & 63;
    float v = lpart[(size_t)w * 128 + lane] + lpart[(size_t)w * 128 + lane + 64];
#pragma unroll
    for (int off = 32; off > 0; off >>= 1) v += __shfl_down(v, off);
    if (lane == 0) {
        float div = (float)((L_ - 2 * (w + 1)) * B_);
        out1[w] = v / div;
    }
}

// -------------------- launch --------------------
extern "C" void kernel_launch(void* const* d_in, const int* in_sizes, int n_in,
                              void* d_out, int out_size, void* d_ws, size_t ws_size,
                              hipStream_t stream)
{
    const float* x     = (const float*)d_in[0];
    const float* cw    = (const float*)d_in[1];
    const float* cb    = (const float*)d_in[2];
    const float* gamma = (const float*)d_in[3];
    const float* beta  = (const float*)d_in[4];
    const float* tw    = (const float*)d_in[5];
    const float* tb    = (const float*)d_in[6];
    const int*   perm  = (const int*)d_in[7];

    float* out0 = (float*)d_out;
    float* out1 = out0 + (size_t)B_ * C_ * L_;

    char* ws = (char*)d_ws;
    __hip_bfloat16* Zb = (__hip_bfloat16*)ws;   ws += (size_t)N_ * C_ * 2;
    __hip_bfloat16* Wt = (__hip_bfloat16*)ws;   ws += (size_t)KSTEPS * C_ * C_ * 2;
    float* qt    = (float*)ws;                  ws += (size_t)KSTEPS * QSTR * 4;
    float* ssum  = (float*)ws;                  ws += C_ * 4;
    float* ssq   = (float*)ws;                  ws += C_ * 4;
    float* lpart = (float*)ws;                  ws += (size_t)KSTEPS * 128 * 4;

    stats_wt_kernel<<<448, 256, 0, stream>>>(x, cw, cb, ssum, ssq, tw, Wt);

    dim3 gcv(64, 16);
    conv_norm_kernel<<<gcv, 256, 0, stream>>>(x, cw, cb, ssum, ssq, gamma, beta, Zb, out0);

    dim3 gq(128, KSTEPS);
    qmfma_kernel<<<gq, 512, 0, stream>>>(Zb, Wt, tb, qt);

    dim3 gl(128, KSTEPS);
    loss_kernel<<<gl, 256, 0, stream>>>(qt, perm, lpart);
    finalize_loss_kernel<<<1, 768, 0, stream>>>(lpart, out1);
}

// Round 10
// 171.681 us; speedup vs baseline: 1.2408x; 1.2153x over previous
//
#include <hip/hip_runtime.h>
#include <hip/hip_bf16.h>
#include <math.h>

constexpr int B_ = 16;
constexpr int T_ = 10240;
constexpr int C_ = 256;
constexpr int KW = 10;
constexpr int L_ = 2047;
constexpr int N_ = B_ * L_;      // 32752
constexpr int KSTEPS = 12;
constexpr float EPS_ = 1e-5f;
constexpr int QSTR = 32768;      // per-k stride of transposed q (2048*16)

typedef short bf16x8 __attribute__((ext_vector_type(8)));
typedef float f32x4  __attribute__((ext_vector_type(4)));

// -------------------- fused: conv+relu+BN-stats  ∪  W-transpose --------------------
// Stats: 512 blocks = (b, 64-l tile) — ~3 blocks/CU for latency hiding (round-9's
// 1-block/CU per-channel variant was latency-starved: 80 µs cold, VALUBusy 4.7%).
// Sliding register window: 5 broadcast ds_reads per output (proven round 7/8).
__global__ __launch_bounds__(256) void stats_wt_kernel(
    const float* __restrict__ x, const float* __restrict__ cw, const float* __restrict__ cb,
    float* __restrict__ ssum, float* __restrict__ ssq,
    const float* __restrict__ tw, __hip_bfloat16* __restrict__ Wt)
{
    __shared__ float smem[64 * 65];
    const int bid = blockIdx.x;
    if (bid < 512) {
        const int b  = bid & 15;
        const int l0 = (bid >> 4) * 64;
        const int cnt = min(64, L_ - l0);     // last tile: 63
        const int c = threadIdx.x;
        float* xs = smem;
        const float* xb = x + (size_t)b * T_;
        for (int i = threadIdx.x; i < cnt * 5 + 5; i += 256) xs[i] = xb[l0 * 5 + i];
        float w[KW];
#pragma unroll
        for (int j = 0; j < KW; ++j) w[j] = cw[c * KW + j];
        const float bias = cb[c];
        __syncthreads();
        float s = 0.f, s2 = 0.f;
        float xw[KW];
#pragma unroll
        for (int j = 0; j < KW; ++j) xw[j] = xs[j];
#pragma unroll 2
        for (int dl = 0; dl < cnt; ++dl) {
            float v = bias;
#pragma unroll
            for (int j = 0; j < KW; ++j) v = fmaf(xw[j], w[j], v);
            v = fmaxf(v, 0.f);
            s += v;
            s2 = fmaf(v, v, s2);
            // shift window by stride 5; staged cnt*5+5 floats keep used reads in-bounds
#pragma unroll
            for (int j = 0; j < 5; ++j) xw[j] = xw[j + 5];
#pragma unroll
            for (int j = 0; j < 5; ++j) xw[j + 5] = xs[dl * 5 + 10 + j];
        }
        atomicAdd(&ssum[c], s);
        atomicAdd(&ssq[c], s2);
    } else {
        const int idx = bid - 512;            // 0..191
        const int k  = idx >> 4;
        const int c0 = ((idx & 15) >> 2) * 64, j0 = (idx & 3) * 64;
        float (*tile)[65] = (float(*)[65])smem;
        for (int i = threadIdx.x; i < 64 * 64; i += 256) {
            int c = i >> 6, j = i & 63;
            tile[c][j] = tw[((size_t)k * C_ + (c0 + c)) * C_ + j0 + j];
        }
        __syncthreads();
        for (int i = threadIdx.x; i < 64 * 64; i += 256) {
            int j = i >> 6, c = i & 63;
            Wt[((size_t)k * C_ + (j0 + j)) * C_ + c0 + c] = __float2bfloat16(tile[c][j]);
        }
    }
}

// -------------------- conv+relu+normalize (BN finalize fused) → out0 + Zb -----------
__global__ __launch_bounds__(256) void conv_norm_kernel(
    const float* __restrict__ x, const float* __restrict__ cw, const float* __restrict__ cb,
    const float* __restrict__ ssum, const float* __restrict__ ssq,
    const float* __restrict__ gamma, const float* __restrict__ beta,
    __hip_bfloat16* __restrict__ Zb, float* __restrict__ out0)
{
    const int b  = blockIdx.y;
    const int l0 = blockIdx.x * 32;
    const int cnt = min(32, L_ - l0);
    const int c = threadIdx.x;
    __shared__ float xs[32 * 5 + 8];
    __shared__ float zt[32][257];
    const float* xb = x + (size_t)b * T_;
    for (int i = threadIdx.x; i < cnt * 5 + 5; i += 256) xs[i] = xb[l0 * 5 + i];
    float w[KW];
#pragma unroll
    for (int j = 0; j < KW; ++j) w[j] = cw[c * KW + j];
    const float bias = cb[c];
    const float inv_n = 1.0f / (float)N_;
    const float mu  = ssum[c] * inv_n;
    const float var = ssq[c] * inv_n - mu * mu;
    const float sc  = gamma[c] * rsqrtf(var + EPS_);
    const float sh  = beta[c] - mu * sc;
    __syncthreads();
    for (int dl = 0; dl < cnt; ++dl) {
        float v = bias;
#pragma unroll
        for (int j = 0; j < KW; ++j) v = fmaf(xs[dl * 5 + j], w[j], v);
        v = fmaxf(v, 0.f);
        float z = fmaf(v, sc, sh);
        Zb[((size_t)(b * L_ + l0 + dl)) * C_ + c] = __float2bfloat16(z);
        zt[dl][c] = z;
    }
    __syncthreads();
    const int lq  = threadIdx.x & 31;
    const int cr0 = threadIdx.x >> 5;      // 0..7
    if (lq < cnt) {
#pragma unroll
        for (int i = 0; i < 32; ++i) {
            int cr = cr0 * 32 + i;
            out0[((size_t)(b * C_ + cr)) * L_ + l0 + lq] = zt[lq][cr];
        }
    }
}

// -------------------- q kernel: 8 waves x 32 cols (round-3 best, single launch) -----
__global__ __launch_bounds__(512, 4) void qmfma_kernel(
    const __hip_bfloat16* __restrict__ Zb, const __hip_bfloat16* __restrict__ Wt,
    const float* __restrict__ tb, float* __restrict__ qt)
{
    const int k   = blockIdx.y;
    const int grp = blockIdx.x;
    const __hip_bfloat16* __restrict__ Wk = Wt + (size_t)k * C_ * C_;

    __shared__ __hip_bfloat16 zs[4][32 * 256];   // 16B chunk j of row r at slot j^(r&7)
    __shared__ float qacc[8][256];

    const int tid  = threadIdx.x;
    const int lane = tid & 63, wave = tid >> 6;   // wave 0..7
    const int n16  = lane & 15, quad = lane >> 4;
    const int sw   = n16 & 7;
    const int row0 = grp * 8 * 32;

    // ---- W resident: col = 32*wave + ct*16 + n16 ; kk = it*32 + quad*8 + j ----
    bf16x8 wfrag[2][8];
    {
        const __hip_bfloat16* wb = Wk + ((size_t)(32 * wave + n16)) * C_ + quad * 8;
#pragma unroll
        for (int ct = 0; ct < 2; ++ct)
#pragma unroll
            for (int it = 0; it < 8; ++it)
                wfrag[ct][it] = *(const bf16x8*)(wb + ct * 16 * C_ + it * 32);
    }
    float4 bias4[2];
#pragma unroll
    for (int ct = 0; ct < 2; ++ct)
        bias4[ct] = *(const float4*)(tb + k * C_ + 32 * wave + ct * 16 + quad * 4);

    // staging: per wave 2 instrs; instr i covers chunks i*512 + wave*64 + lane
#define STAGE(buf, t) do {                                                                  \
    _Pragma("unroll")                                                                       \
    for (int i_ = 0; i_ < 2; ++i_) {                                                        \
        int ch = i_ * 512 + wave * 64 + lane;                                               \
        int rr = ch >> 5;                                                                   \
        int rg = row0 + (t) * 32 + rr; if (rg > N_ - 1) rg = N_ - 1;                        \
        int jj = (lane & 31) ^ (rr & 7);                                                    \
        __builtin_amdgcn_global_load_lds(                                                   \
            (const __attribute__((address_space(1))) void*)(Zb + (size_t)rg * C_ + jj * 8), \
            (__attribute__((address_space(3))) void*)(&zs[buf][i_ * 4096 + wave * 512]),    \
            16, 0, 0);                                                                      \
    }                                                                                       \
} while (0)

    // prologue: stage tiles 0 and 1, drain once (also drains wfrag/bias loads)
    STAGE(0, 0);
    STAGE(1, 1);
    asm volatile("s_waitcnt vmcnt(0)" ::: "memory");

#pragma unroll
    for (int t = 0; t < 8; ++t) {
        if (t < 6) STAGE((t + 2) & 3, t + 2);
        if (t < 6)                { asm volatile("s_waitcnt vmcnt(4)" ::: "memory"); }
        else if (t == 6)          { asm volatile("s_waitcnt vmcnt(2)" ::: "memory"); }
        else                      { asm volatile("s_waitcnt vmcnt(0)" ::: "memory"); }
        __builtin_amdgcn_s_barrier();

        const __hip_bfloat16* zsp = (const __hip_bfloat16*)zs[t & 3];

        f32x4 acc[2][2];
#pragma unroll
        for (int rt = 0; rt < 2; ++rt)
#pragma unroll
            for (int ct = 0; ct < 2; ++ct) acc[rt][ct] = f32x4{0.f, 0.f, 0.f, 0.f};

        __builtin_amdgcn_s_setprio(1);
#pragma unroll
        for (int it = 0; it < 8; ++it) {
            const int js = (it * 4 + quad) ^ sw;
            bf16x8 zf0 = *(const bf16x8*)(zsp + n16 * 256 + js * 8);
            bf16x8 zf1 = *(const bf16x8*)(zsp + (n16 + 16) * 256 + js * 8);
#pragma unroll
            for (int ct = 0; ct < 2; ++ct) {
                acc[0][ct] = __builtin_amdgcn_mfma_f32_16x16x32_bf16(
                    wfrag[ct][it], zf0, acc[0][ct], 0, 0, 0);
                acc[1][ct] = __builtin_amdgcn_mfma_f32_16x16x32_bf16(
                    wfrag[ct][it], zf1, acc[1][ct], 0, 0, 0);
            }
        }
        __builtin_amdgcn_s_setprio(0);

        // ---- epilogue: zrow = rt*16+n16 ; wcols = 32w + ct*16 + quad*4 + r ----
#pragma unroll
        for (int rt = 0; rt < 2; ++rt) {
            const int row = rt * 16 + n16;
            float s = 0.f;
#pragma unroll
            for (int ct = 0; ct < 2; ++ct) {
                const int j  = 4 * wave + 2 * ct + (quad >> 1);
                const char* zp = (const char*)zsp + row * 512 + ((j ^ sw) << 4) + (quad & 1) * 8;
                uint2 zz = *(const uint2*)zp;
                float z0 = __uint_as_float(zz.x << 16);
                float z1 = __uint_as_float(zz.x & 0xffff0000u);
                float z2 = __uint_as_float(zz.y << 16);
                float z3 = __uint_as_float(zz.y & 0xffff0000u);
                s = fmaf(acc[rt][ct][0] + bias4[ct].x, z0, s);
                s = fmaf(acc[rt][ct][1] + bias4[ct].y, z1, s);
                s = fmaf(acc[rt][ct][2] + bias4[ct].z, z2, s);
                s = fmaf(acc[rt][ct][3] + bias4[ct].w, z3, s);
            }
            s += __shfl_xor(s, 16);
            s += __shfl_xor(s, 32);
            if (lane < 16) qacc[wave][t * 32 + row] = s;   // wave-private slice
        }
        // no end-of-tile barrier: buffer t&3 is next overwritten at iter t+2,
        // separated by the top barrier of iter t+1.
    }
#undef STAGE

    __syncthreads();
    // ---- block-end: reduce 8 wave partials per row, write transposed qt ----
    if (tid < 256) {
        int rg = row0 + tid;
        if (rg < N_) {
            float qv = 0.f;
#pragma unroll
            for (int w2 = 0; w2 < 8; ++w2) qv += qacc[w2][tid];
            int b = rg / L_;
            int l = rg - b * L_;
            qt[(size_t)k * QSTR + (l << 4) + b] = qv;
        }
    }
}

// -------------------- loss: gathers + fast LSE → per-block partials (no atomics) -----
__global__ __launch_bounds__(256) void loss_kernel(
    const float* __restrict__ qt, const int* __restrict__ perm, float* __restrict__ lpart)
{
    const int k = blockIdx.y + 1;                 // 1..12
    const float* qk = qt + (size_t)(k - 1) * QSTR;
    const int nval = B_ * (L_ - k);
    const int idx = blockIdx.x * 256 + threadIdx.x;

    float contrib = 0.f;
    if (idx < nval) {
        int b = idx & 15;
        int l = k + (idx >> 4);
        float f0 = qk[(l << 4) | b];
        int pl = perm[l];
        const float* qn = qk + ((size_t)pl << 4);
        float f[10];
#pragma unroll
        for (int n = 0; n < 10; ++n) f[n] = qn[(b + 15 - n) & 15];
        float m = f0;
#pragma unroll
        for (int i = 0; i < 10; ++i) m = fmaxf(m, f[i]);
        float se = __expf(f0 - m), fs = f0;
#pragma unroll
        for (int i = 0; i < 10; ++i) { se += __expf(f[i] - m); fs += f[i]; }
        contrib = 11.f * (m + __logf(se)) - fs;
    }

    __shared__ float red[4];
#pragma unroll
    for (int off = 32; off > 0; off >>= 1) contrib += __shfl_down(contrib, off);
    const int lane = threadIdx.x & 63;
    const int wave = threadIdx.x >> 6;
    if (lane == 0) red[wave] = contrib;
    __syncthreads();
    if (threadIdx.x == 0)
        lpart[(size_t)(k - 1) * 128 + blockIdx.x] = red[0] + red[1] + red[2] + red[3];
}

// 12 waves, wave k sums its 128 partials and divides — no lacc, no memset for loss.
__global__ __launch_bounds__(768) void finalize_loss_kernel(
    const float* __restrict__ lpart, float* __restrict__ out1)
{
    const int w = threadIdx.x >> 6;               // k index 0..11
    const int lane = threadIdx.x & 63;
    float v = lpart[(size_t)w * 128 + lane] + lpart[(size_t)w * 128 + lane + 64];
#pragma unroll
    for (int off = 32; off > 0; off >>= 1) v += __shfl_down(v, off);
    if (lane == 0) {
        float div = (float)((L_ - 2 * (w + 1)) * B_);
        out1[w] = v / div;
    }
}

// -------------------- launch --------------------
extern "C" void kernel_launch(void* const* d_in, const int* in_sizes, int n_in,
                              void* d_out, int out_size, void* d_ws, size_t ws_size,
                              hipStream_t stream)
{
    const float* x     = (const float*)d_in[0];
    const float* cw    = (const float*)d_in[1];
    const float* cb    = (const float*)d_in[2];
    const float* gamma = (const float*)d_in[3];
    const float* beta  = (const float*)d_in[4];
    const float* tw    = (const float*)d_in[5];
    const float* tb    = (const float*)d_in[6];
    const int*   perm  = (const int*)d_in[7];

    float* out0 = (float*)d_out;
    float* out1 = out0 + (size_t)B_ * C_ * L_;

    char* ws = (char*)d_ws;
    __hip_bfloat16* Zb = (__hip_bfloat16*)ws;   ws += (size_t)N_ * C_ * 2;
    __hip_bfloat16* Wt = (__hip_bfloat16*)ws;   ws += (size_t)KSTEPS * C_ * C_ * 2;
    float* qt    = (float*)ws;                  ws += (size_t)KSTEPS * QSTR * 4;
    float* ssum  = (float*)ws;                  ws += C_ * 4;
    float* ssq   = (float*)ws;                  ws += C_ * 4;
    float* lpart = (float*)ws;                  ws += (size_t)KSTEPS * 128 * 4;

    // zero only ssum/ssq (2 KB) — loss path is atomic-free
    hipMemsetAsync(ssum, 0, 2 * C_ * sizeof(float), stream);

    stats_wt_kernel<<<704, 256, 0, stream>>>(x, cw, cb, ssum, ssq, tw, Wt);

    dim3 gcv(64, 16);
    conv_norm_kernel<<<gcv, 256, 0, stream>>>(x, cw, cb, ssum, ssq, gamma, beta, Zb, out0);

    dim3 gq(128, KSTEPS);
    qmfma_kernel<<<gq, 512, 0, stream>>>(Zb, Wt, tb, qt);

    dim3 gl(128, KSTEPS);
    loss_kernel<<<gl, 256, 0, stream>>>(qt, perm, lpart);
    finalize_loss_kernel<<<1, 768, 0, stream>>>(lpart, out1);
}